// Round 1
// baseline (590.026 us; speedup 1.0000x reference)
//
#include <hip/hip_runtime.h>

#define NN 50000
#define NE 800000
#define DD 128

// workspace layout, element (4-byte) offsets, padded to 256-elem boundaries
#define OF_DEG   0            // int[NN]
#define OF_DINV  50176        // float[NN]
#define OF_OFFS  100352       // int[NN+1]
#define OF_CURS  150784       // int[NN]
#define OF_CSRS  200960       // int[NE]
#define OF_CSRW  1000960      // float[NE]
#define OF_H     1800960      // float[NN*DD]  (16B-aligned: 1800960*4 % 16 == 0)
#define OF_AGG   8201216      // float[NN*DD]
// total ~58.4 MB of ws

__global__ void k_init_deg(int* __restrict__ deg) {
    int i = blockIdx.x * blockDim.x + threadIdx.x;
    if (i < NN) deg[i] = 1;   // self-loop contributes 1
}

__global__ void k_count(const int* __restrict__ dst, int* __restrict__ deg) {
    int e = blockIdx.x * blockDim.x + threadIdx.x;
    if (e < NE) atomicAdd(&deg[dst[e]], 1);
}

__global__ void k_dinv(const int* __restrict__ deg, float* __restrict__ dinv) {
    int i = blockIdx.x * blockDim.x + threadIdx.x;
    if (i < NN) dinv[i] = rsqrtf((float)deg[i]);  // deg >= 1 always
}

// single-block exclusive scan over in-degrees (deg[i]-1) -> CSR row offsets
__global__ void k_scan(const int* __restrict__ deg, int* __restrict__ offs,
                       int* __restrict__ curs) {
    __shared__ int part[1024];
    int tid = threadIdx.x;
    const int chunk = (NN + 1023) / 1024;  // 49
    int start = tid * chunk;
    int end = start + chunk;
    if (start > NN) start = NN;
    if (end > NN) end = NN;
    int s = 0;
    for (int i = start; i < end; ++i) s += deg[i] - 1;
    part[tid] = s;
    __syncthreads();
    // Hillis-Steele inclusive scan
    for (int off = 1; off < 1024; off <<= 1) {
        int v = (tid >= off) ? part[tid - off] : 0;
        __syncthreads();
        part[tid] += v;
        __syncthreads();
    }
    int base = part[tid] - s;  // exclusive prefix
    for (int i = start; i < end; ++i) {
        offs[i] = base;
        curs[i] = base;
        base += deg[i] - 1;
    }
    if (tid == 1023) offs[NN] = part[1023];
}

__global__ void k_place(const int* __restrict__ src, const int* __restrict__ dst,
                        const float* __restrict__ dinv, int* __restrict__ curs,
                        int* __restrict__ csr_src, float* __restrict__ csr_w) {
    int e = blockIdx.x * blockDim.x + threadIdx.x;
    if (e < NE) {
        int s = src[e], d = dst[e];
        int p = atomicAdd(&curs[d], 1);
        csr_src[p] = s;
        csr_w[p] = dinv[s] * dinv[d];
    }
}

// Y[r][j] = sum_k X[r][k] * W[k][j].  One thread per column j; W column held in
// 128 VGPRs across the whole block's row range; x rows staged 8-at-a-time in
// LDS and read as broadcast float4 (conflict-free broadcast).
__global__ __launch_bounds__(128, 2) void k_gemm(const float* __restrict__ X,
                                                 const float* __restrict__ W,
                                                 float* __restrict__ Y) {
    const int j = threadIdx.x;
    float wreg[DD];
#pragma unroll
    for (int k = 0; k < DD; ++k) wreg[k] = W[k * DD + j];
    __shared__ float xs[8 * DD];
    const int RPB = 25;  // 2000 blocks * 25 rows = 50000
    int r0 = blockIdx.x * RPB;
    int r1 = r0 + RPB;
    if (r1 > NN) r1 = NN;
    for (int rb = r0; rb < r1; rb += 8) {
        int nr = r1 - rb;
        if (nr > 8) nr = 8;
        __syncthreads();
        for (int q = 0; q < 8; ++q)
            if (q < nr) xs[q * DD + j] = X[(size_t)(rb + q) * DD + j];
        __syncthreads();
        for (int rr = 0; rr < nr; ++rr) {
            const float4* xr = (const float4*)(xs + rr * DD);
            float acc = 0.f;
#pragma unroll
            for (int k4 = 0; k4 < DD / 4; ++k4) {
                float4 xv = xr[k4];
                acc += xv.x * wreg[4 * k4] + xv.y * wreg[4 * k4 + 1] +
                       xv.z * wreg[4 * k4 + 2] + xv.w * wreg[4 * k4 + 3];
            }
            Y[(size_t)(rb + rr) * DD + j] = acc;
        }
    }
}

// out[i] = relu( dinv[i]^2 * h[i] + sum_{e: dst==i} w_e * h[src_e] + bias )
// one wave per node; lane owns a float2 column pair -> each edge is a single
// coalesced 512B row read across the wave.
__global__ void k_agg(const float* __restrict__ h, const float* __restrict__ dinv,
                      const int* __restrict__ offs, const int* __restrict__ csr_src,
                      const float* __restrict__ csr_w, const float* __restrict__ bias,
                      float* __restrict__ out) {
    int gid = blockIdx.x * blockDim.x + threadIdx.x;
    int node = gid >> 6;
    int lane = gid & 63;
    if (node >= NN) return;
    float di = dinv[node];
    float sw = di * di;
    float2 hv = ((const float2*)(h + (size_t)node * DD))[lane];
    float ax = hv.x * sw, ay = hv.y * sw;
    int e1 = offs[node + 1];
    for (int e = offs[node]; e < e1; ++e) {
        int s = csr_src[e];
        float w = csr_w[e];
        float2 v = ((const float2*)(h + (size_t)s * DD))[lane];
        ax += w * v.x;
        ay += w * v.y;
    }
    float2 bv = ((const float2*)bias)[lane];
    float2 o;
    o.x = fmaxf(ax + bv.x, 0.f);
    o.y = fmaxf(ay + bv.y, 0.f);
    ((float2*)(out + (size_t)node * DD))[lane] = o;
}

extern "C" void kernel_launch(void* const* d_in, const int* in_sizes, int n_in,
                              void* d_out, int out_size, void* d_ws, size_t ws_size,
                              hipStream_t stream) {
    const float* x  = (const float*)d_in[0];
    const int*   ei = (const int*)d_in[1];
    const float* W1 = (const float*)d_in[2];
    const float* b1 = (const float*)d_in[3];
    const float* W2 = (const float*)d_in[4];
    const float* b2 = (const float*)d_in[5];
    float* out = (float*)d_out;

    const int* src = ei;        // edge_index[0]
    const int* dst = ei + NE;   // edge_index[1]

    int*   wsi  = (int*)d_ws;
    float* wsf  = (float*)d_ws;
    int*   deg  = wsi + OF_DEG;
    float* dinv = wsf + OF_DINV;
    int*   offs = wsi + OF_OFFS;
    int*   curs = wsi + OF_CURS;
    int*   csrs = wsi + OF_CSRS;
    float* csrw = wsf + OF_CSRW;
    float* hbuf = wsf + OF_H;
    float* abuf = wsf + OF_AGG;

    hipLaunchKernelGGL(k_init_deg, dim3((NN + 255) / 256), dim3(256), 0, stream, deg);
    hipLaunchKernelGGL(k_count,    dim3((NE + 255) / 256), dim3(256), 0, stream, dst, deg);
    hipLaunchKernelGGL(k_dinv,     dim3((NN + 255) / 256), dim3(256), 0, stream, deg, dinv);
    hipLaunchKernelGGL(k_scan,     dim3(1), dim3(1024), 0, stream, deg, offs, curs);
    hipLaunchKernelGGL(k_place,    dim3((NE + 255) / 256), dim3(256), 0, stream,
                       src, dst, dinv, curs, csrs, csrw);

    // layer 1: h = x @ W1 ; agg -> +b1, relu
    hipLaunchKernelGGL(k_gemm, dim3(2000), dim3(128), 0, stream, x, W1, hbuf);
    hipLaunchKernelGGL(k_agg,  dim3((NN * 64 + 255) / 256), dim3(256), 0, stream,
                       hbuf, dinv, offs, csrs, csrw, b1, abuf);
    // layer 2
    hipLaunchKernelGGL(k_gemm, dim3(2000), dim3(128), 0, stream, abuf, W2, hbuf);
    hipLaunchKernelGGL(k_agg,  dim3((NN * 64 + 255) / 256), dim3(256), 0, stream,
                       hbuf, dinv, offs, csrs, csrw, b2, out);
}

// Round 2
// 495.974 us; speedup vs baseline: 1.1896x; 1.1896x over previous
//
#include <hip/hip_runtime.h>

#define NN 50000
#define NE 800000
#define DD 128
#define SCAN_NB 196   // ceil(NN/256)

// workspace layout, element (4-byte) offsets, padded to 256-elem boundaries
#define OF_DEG   0            // int[NN]
#define OF_DINV  50176        // float[NN]
#define OF_OFFS  100352       // int[NN+1]
#define OF_CURS  150784       // int[NN]
#define OF_BSUM  200960       // int[SCAN_NB]
#define OF_BPRE  201216       // int[SCAN_NB]
#define OF_CSRS  201472       // int[NE]
#define OF_CSRW  1001472      // float[NE]
#define OF_H     1801472      // float[NN*DD]  (16B-aligned)
#define OF_AGG   8201728      // float[NN*DD]

__global__ void k_init_deg(int* __restrict__ deg) {
    int i = blockIdx.x * blockDim.x + threadIdx.x;
    if (i < NN) deg[i] = 1;   // self-loop contributes 1
}

__global__ void k_count(const int* __restrict__ dst, int* __restrict__ deg) {
    int e = blockIdx.x * blockDim.x + threadIdx.x;
    if (e < NE) atomicAdd(&deg[dst[e]], 1);
}

// hierarchical scan over in-degrees (deg[i]-1), phase 1: per-block exclusive
__global__ void k_scan1(const int* __restrict__ deg, int* __restrict__ offs,
                        int* __restrict__ bsum) {
    __shared__ int sh[256];
    int tid = threadIdx.x;
    int i = blockIdx.x * 256 + tid;
    int v = (i < NN) ? (deg[i] - 1) : 0;
    sh[tid] = v;
    __syncthreads();
    for (int off = 1; off < 256; off <<= 1) {
        int t = (tid >= off) ? sh[tid - off] : 0;
        __syncthreads();
        sh[tid] += t;
        __syncthreads();
    }
    if (i < NN) offs[i] = sh[tid] - v;  // exclusive, block-local
    if (tid == 255) bsum[blockIdx.x] = sh[255];
}

// phase 2: single small block scans the 196 block sums
__global__ void k_scan2(const int* __restrict__ bsum, int* __restrict__ bpre,
                        int* __restrict__ offs) {
    __shared__ int sh[256];
    int tid = threadIdx.x;
    int v = (tid < SCAN_NB) ? bsum[tid] : 0;
    sh[tid] = v;
    __syncthreads();
    for (int off = 1; off < 256; off <<= 1) {
        int t = (tid >= off) ? sh[tid - off] : 0;
        __syncthreads();
        sh[tid] += t;
        __syncthreads();
    }
    if (tid < SCAN_NB) bpre[tid] = sh[tid] - v;
    if (tid == 255) offs[NN] = sh[255];  // total non-self-loop edges
}

// phase 3: add block prefix; also init curs and compute dinv (fused)
__global__ void k_scan3(int* __restrict__ offs, const int* __restrict__ bpre,
                        int* __restrict__ curs, const int* __restrict__ deg,
                        float* __restrict__ dinv) {
    int i = blockIdx.x * 256 + threadIdx.x;
    if (i < NN) {
        int o = offs[i] + bpre[blockIdx.x];
        offs[i] = o;
        curs[i] = o;
        dinv[i] = rsqrtf((float)deg[i]);
    }
}

__global__ void k_place(const int* __restrict__ src, const int* __restrict__ dst,
                        const float* __restrict__ dinv, int* __restrict__ curs,
                        int* __restrict__ csr_src, float* __restrict__ csr_w) {
    int e = blockIdx.x * blockDim.x + threadIdx.x;
    if (e < NE) {
        int s = src[e], d = dst[e];
        int p = atomicAdd(&curs[d], 1);
        csr_src[p] = s;
        csr_w[p] = dinv[s] * dinv[d];
    }
}

// Y[r][j] = sum_k X[r][k] * W[k][j].  One thread per column j; W column in
// 128 VGPRs; x rows staged 8-at-a-time in LDS, read as broadcast float4.
__global__ __launch_bounds__(128, 2) void k_gemm(const float* __restrict__ X,
                                                 const float* __restrict__ W,
                                                 float* __restrict__ Y) {
    const int j = threadIdx.x;
    float wreg[DD];
#pragma unroll
    for (int k = 0; k < DD; ++k) wreg[k] = W[k * DD + j];
    __shared__ float xs[8 * DD];
    const int RPB = 25;  // 2000 blocks * 25 rows = 50000
    int r0 = blockIdx.x * RPB;
    int r1 = r0 + RPB;
    if (r1 > NN) r1 = NN;
    for (int rb = r0; rb < r1; rb += 8) {
        int nr = r1 - rb;
        if (nr > 8) nr = 8;
        __syncthreads();
        for (int q = 0; q < 8; ++q)
            if (q < nr) xs[q * DD + j] = X[(size_t)(rb + q) * DD + j];
        __syncthreads();
        for (int rr = 0; rr < nr; ++rr) {
            const float4* xr = (const float4*)(xs + rr * DD);
            float acc = 0.f;
#pragma unroll
            for (int k4 = 0; k4 < DD / 4; ++k4) {
                float4 xv = xr[k4];
                acc += xv.x * wreg[4 * k4] + xv.y * wreg[4 * k4 + 1] +
                       xv.z * wreg[4 * k4 + 2] + xv.w * wreg[4 * k4 + 3];
            }
            Y[(size_t)(rb + rr) * DD + j] = acc;
        }
    }
}

// out[i] = relu( dinv[i]^2 * h[i] + sum_{e: dst==i} w_e * h[src_e] + bias )
// one wave per node; lane owns a float2 column pair -> one coalesced 512B
// row read per edge.
__global__ void k_agg(const float* __restrict__ h, const float* __restrict__ dinv,
                      const int* __restrict__ offs, const int* __restrict__ csr_src,
                      const float* __restrict__ csr_w, const float* __restrict__ bias,
                      float* __restrict__ out) {
    int gid = blockIdx.x * blockDim.x + threadIdx.x;
    int node = gid >> 6;
    int lane = gid & 63;
    if (node >= NN) return;
    float di = dinv[node];
    float sw = di * di;
    float2 hv = ((const float2*)(h + (size_t)node * DD))[lane];
    float ax = hv.x * sw, ay = hv.y * sw;
    int e1 = offs[node + 1];
    for (int e = offs[node]; e < e1; ++e) {
        int s = csr_src[e];
        float w = csr_w[e];
        float2 v = ((const float2*)(h + (size_t)s * DD))[lane];
        ax += w * v.x;
        ay += w * v.y;
    }
    float2 bv = ((const float2*)bias)[lane];
    float2 o;
    o.x = fmaxf(ax + bv.x, 0.f);
    o.y = fmaxf(ay + bv.y, 0.f);
    ((float2*)(out + (size_t)node * DD))[lane] = o;
}

extern "C" void kernel_launch(void* const* d_in, const int* in_sizes, int n_in,
                              void* d_out, int out_size, void* d_ws, size_t ws_size,
                              hipStream_t stream) {
    const float* x  = (const float*)d_in[0];
    const int*   ei = (const int*)d_in[1];
    const float* W1 = (const float*)d_in[2];
    const float* b1 = (const float*)d_in[3];
    const float* W2 = (const float*)d_in[4];
    const float* b2 = (const float*)d_in[5];
    float* out = (float*)d_out;

    const int* src = ei;        // edge_index[0]
    const int* dst = ei + NE;   // edge_index[1]

    int*   wsi  = (int*)d_ws;
    float* wsf  = (float*)d_ws;
    int*   deg  = wsi + OF_DEG;
    float* dinv = wsf + OF_DINV;
    int*   offs = wsi + OF_OFFS;
    int*   curs = wsi + OF_CURS;
    int*   bsum = wsi + OF_BSUM;
    int*   bpre = wsi + OF_BPRE;
    int*   csrs = wsi + OF_CSRS;
    float* csrw = wsf + OF_CSRW;
    float* hbuf = wsf + OF_H;
    float* abuf = wsf + OF_AGG;

    hipLaunchKernelGGL(k_init_deg, dim3((NN + 255) / 256), dim3(256), 0, stream, deg);
    hipLaunchKernelGGL(k_count,    dim3((NE + 255) / 256), dim3(256), 0, stream, dst, deg);
    hipLaunchKernelGGL(k_scan1,    dim3(SCAN_NB), dim3(256), 0, stream, deg, offs, bsum);
    hipLaunchKernelGGL(k_scan2,    dim3(1), dim3(256), 0, stream, bsum, bpre, offs);
    hipLaunchKernelGGL(k_scan3,    dim3(SCAN_NB), dim3(256), 0, stream, offs, bpre, curs, deg, dinv);
    hipLaunchKernelGGL(k_place,    dim3((NE + 255) / 256), dim3(256), 0, stream,
                       src, dst, dinv, curs, csrs, csrw);

    // layer 1: h = x @ W1 ; agg -> +b1, relu
    hipLaunchKernelGGL(k_gemm, dim3(2000), dim3(128), 0, stream, x, W1, hbuf);
    hipLaunchKernelGGL(k_agg,  dim3((NN * 64 + 255) / 256), dim3(256), 0, stream,
                       hbuf, dinv, offs, csrs, csrw, b1, abuf);
    // layer 2
    hipLaunchKernelGGL(k_gemm, dim3(2000), dim3(128), 0, stream, abuf, W2, hbuf);
    hipLaunchKernelGGL(k_agg,  dim3((NN * 64 + 255) / 256), dim3(256), 0, stream,
                       hbuf, dinv, offs, csrs, csrw, b2, out);
}

// Round 3
// 416.517 us; speedup vs baseline: 1.4166x; 1.1908x over previous
//
#include <hip/hip_runtime.h>

#define NN 50000
#define NE 800000
#define DD 128
#define SCAN_NB 196   // ceil(NN/256)

// workspace layout, element (4-byte) offsets
#define OF_DEG   0            // int[NN]
#define OF_DINV  50176        // float[NN]
#define OF_OFFS  100352       // int[NN+1]
#define OF_CURS  150784       // int[NN]
#define OF_BSUM  200960       // int[SCAN_NB]
#define OF_BPRE  201216       // int[SCAN_NB]
#define OF_CSRS  201472       // int[NE]
#define OF_CSRW  1001472      // float[NE]
#define OF_H     1801472      // float[NN*DD]  (16B-aligned)
#define OF_AGG   8201728      // float[NN*DD]

__global__ void k_init_deg(int* __restrict__ deg) {
    int i = blockIdx.x * blockDim.x + threadIdx.x;
    if (i < NN) deg[i] = 1;   // self-loop contributes 1
}

__global__ void k_count(const int* __restrict__ dst, int* __restrict__ deg) {
    int e = blockIdx.x * blockDim.x + threadIdx.x;
    if (e < NE) atomicAdd(&deg[dst[e]], 1);
}

// hierarchical scan over in-degrees (deg[i]-1), phase 1: per-block exclusive
__global__ void k_scan1(const int* __restrict__ deg, int* __restrict__ offs,
                        int* __restrict__ bsum) {
    __shared__ int sh[256];
    int tid = threadIdx.x;
    int i = blockIdx.x * 256 + tid;
    int v = (i < NN) ? (deg[i] - 1) : 0;
    sh[tid] = v;
    __syncthreads();
    for (int off = 1; off < 256; off <<= 1) {
        int t = (tid >= off) ? sh[tid - off] : 0;
        __syncthreads();
        sh[tid] += t;
        __syncthreads();
    }
    if (i < NN) offs[i] = sh[tid] - v;  // exclusive, block-local
    if (tid == 255) bsum[blockIdx.x] = sh[255];
}

// phase 2: single small block scans the 196 block sums
__global__ void k_scan2(const int* __restrict__ bsum, int* __restrict__ bpre,
                        int* __restrict__ offs) {
    __shared__ int sh[256];
    int tid = threadIdx.x;
    int v = (tid < SCAN_NB) ? bsum[tid] : 0;
    sh[tid] = v;
    __syncthreads();
    for (int off = 1; off < 256; off <<= 1) {
        int t = (tid >= off) ? sh[tid - off] : 0;
        __syncthreads();
        sh[tid] += t;
        __syncthreads();
    }
    if (tid < SCAN_NB) bpre[tid] = sh[tid] - v;
    if (tid == 255) offs[NN] = sh[255];  // total non-self-loop edges
}

// phase 3: add block prefix; also init curs and compute dinv (fused)
__global__ void k_scan3(int* __restrict__ offs, const int* __restrict__ bpre,
                        int* __restrict__ curs, const int* __restrict__ deg,
                        float* __restrict__ dinv) {
    int i = blockIdx.x * 256 + threadIdx.x;
    if (i < NN) {
        int o = offs[i] + bpre[blockIdx.x];
        offs[i] = o;
        curs[i] = o;
        dinv[i] = rsqrtf((float)deg[i]);
    }
}

__global__ void k_place(const int* __restrict__ src, const int* __restrict__ dst,
                        const float* __restrict__ dinv, int* __restrict__ curs,
                        int* __restrict__ csr_src, float* __restrict__ csr_w) {
    int e = blockIdx.x * blockDim.x + threadIdx.x;
    if (e < NE) {
        int s = src[e], d = dst[e];
        int p = atomicAdd(&curs[d], 1);
        csr_src[p] = s;
        csr_w[p] = dinv[s] * dinv[d];
    }
}

// Y[r][j] = sum_k X[r][k] * W[k][j].  Thread = output column j; W column in
// 128 VGPRs.  x is read straight from global with lane-invariant addresses
// (scalarizes to s_load; no LDS round-trip).  2-row unroll for ILP.
__global__ __launch_bounds__(128) void k_gemm(const float* __restrict__ X,
                                              const float* __restrict__ W,
                                              float* __restrict__ Y) {
    const int j = threadIdx.x;
    float wreg[DD];
#pragma unroll
    for (int k = 0; k < DD; ++k) wreg[k] = W[k * DD + j];
    const int RPB = 25;  // 2000 blocks * 25 rows = 50000
    int r0 = blockIdx.x * RPB;
    int r1 = r0 + RPB;
    if (r1 > NN) r1 = NN;
    int r = r0;
    for (; r + 1 < r1; r += 2) {
        const float4* x0 = (const float4*)(X + (size_t)r * DD);
        const float4* x1 = (const float4*)(X + (size_t)(r + 1) * DD);
        float acc0 = 0.f, acc1 = 0.f;
#pragma unroll
        for (int k4 = 0; k4 < DD / 4; ++k4) {
            float4 a = x0[k4];
            float4 b = x1[k4];
            acc0 += a.x * wreg[4 * k4] + a.y * wreg[4 * k4 + 1] +
                    a.z * wreg[4 * k4 + 2] + a.w * wreg[4 * k4 + 3];
            acc1 += b.x * wreg[4 * k4] + b.y * wreg[4 * k4 + 1] +
                    b.z * wreg[4 * k4 + 2] + b.w * wreg[4 * k4 + 3];
        }
        Y[(size_t)r * DD + j] = acc0;
        Y[(size_t)(r + 1) * DD + j] = acc1;
    }
    if (r < r1) {
        const float4* x0 = (const float4*)(X + (size_t)r * DD);
        float acc0 = 0.f;
#pragma unroll
        for (int k4 = 0; k4 < DD / 4; ++k4) {
            float4 a = x0[k4];
            acc0 += a.x * wreg[4 * k4] + a.y * wreg[4 * k4 + 1] +
                    a.z * wreg[4 * k4 + 2] + a.w * wreg[4 * k4 + 3];
        }
        Y[(size_t)r * DD + j] = acc0;
    }
}

// out[i] = relu( dinv[i]^2 * h[i] + sum_{e: dst==i} w_e * h[src_e] + bias )
// One wave per node.  Row split as 32 lanes x float4 (16B/lane); the two
// wave halves take interleaved edges and we unroll 2x -> 4 independent row
// gathers in flight per wave.  Halves combined with one shfl_xor(32).
__global__ void k_agg(const float* __restrict__ h, const float* __restrict__ dinv,
                      const int* __restrict__ offs, const int* __restrict__ csr_src,
                      const float* __restrict__ csr_w, const float* __restrict__ bias,
                      float* __restrict__ out) {
    int gid = blockIdx.x * blockDim.x + threadIdx.x;
    int node = gid >> 6;
    if (node >= NN) return;
    int lane = threadIdx.x & 63;
    int half = lane >> 5;
    int c = lane & 31;
    const float4* hb = (const float4*)h;  // row r at hb[r*32 + c]
    float4 a0 = {0.f, 0.f, 0.f, 0.f};
    float4 a1 = {0.f, 0.f, 0.f, 0.f};
    int e  = offs[node] + half;
    int e1 = offs[node + 1];
    for (; e + 2 < e1; e += 4) {
        int   s0 = csr_src[e];     float w0 = csr_w[e];
        int   s1 = csr_src[e + 2]; float w1 = csr_w[e + 2];
        float4 v0 = hb[(size_t)s0 * 32 + c];
        float4 v1 = hb[(size_t)s1 * 32 + c];
        a0.x += w0 * v0.x; a0.y += w0 * v0.y; a0.z += w0 * v0.z; a0.w += w0 * v0.w;
        a1.x += w1 * v1.x; a1.y += w1 * v1.y; a1.z += w1 * v1.z; a1.w += w1 * v1.w;
    }
    if (e < e1) {
        int s0 = csr_src[e]; float w0 = csr_w[e];
        float4 v0 = hb[(size_t)s0 * 32 + c];
        a0.x += w0 * v0.x; a0.y += w0 * v0.y; a0.z += w0 * v0.z; a0.w += w0 * v0.w;
    }
    if (half == 0) {  // self-loop term, counted once
        float di = dinv[node];
        float sw = di * di;
        float4 v = hb[(size_t)node * 32 + c];
        a0.x += sw * v.x; a0.y += sw * v.y; a0.z += sw * v.z; a0.w += sw * v.w;
    }
    a0.x += a1.x; a0.y += a1.y; a0.z += a1.z; a0.w += a1.w;
    a0.x += __shfl_xor(a0.x, 32, 64);
    a0.y += __shfl_xor(a0.y, 32, 64);
    a0.z += __shfl_xor(a0.z, 32, 64);
    a0.w += __shfl_xor(a0.w, 32, 64);
    if (half == 0) {
        float4 bv = ((const float4*)bias)[c];
        float4 o;
        o.x = fmaxf(a0.x + bv.x, 0.f);
        o.y = fmaxf(a0.y + bv.y, 0.f);
        o.z = fmaxf(a0.z + bv.z, 0.f);
        o.w = fmaxf(a0.w + bv.w, 0.f);
        ((float4*)(out + (size_t)node * DD))[c] = o;
    }
}

extern "C" void kernel_launch(void* const* d_in, const int* in_sizes, int n_in,
                              void* d_out, int out_size, void* d_ws, size_t ws_size,
                              hipStream_t stream) {
    const float* x  = (const float*)d_in[0];
    const int*   ei = (const int*)d_in[1];
    const float* W1 = (const float*)d_in[2];
    const float* b1 = (const float*)d_in[3];
    const float* W2 = (const float*)d_in[4];
    const float* b2 = (const float*)d_in[5];
    float* out = (float*)d_out;

    const int* src = ei;        // edge_index[0]
    const int* dst = ei + NE;   // edge_index[1]

    int*   wsi  = (int*)d_ws;
    float* wsf  = (float*)d_ws;
    int*   deg  = wsi + OF_DEG;
    float* dinv = wsf + OF_DINV;
    int*   offs = wsi + OF_OFFS;
    int*   curs = wsi + OF_CURS;
    int*   bsum = wsi + OF_BSUM;
    int*   bpre = wsi + OF_BPRE;
    int*   csrs = wsi + OF_CSRS;
    float* csrw = wsf + OF_CSRW;
    float* hbuf = wsf + OF_H;
    float* abuf = wsf + OF_AGG;

    hipLaunchKernelGGL(k_init_deg, dim3((NN + 255) / 256), dim3(256), 0, stream, deg);
    hipLaunchKernelGGL(k_count,    dim3((NE + 255) / 256), dim3(256), 0, stream, dst, deg);
    hipLaunchKernelGGL(k_scan1,    dim3(SCAN_NB), dim3(256), 0, stream, deg, offs, bsum);
    hipLaunchKernelGGL(k_scan2,    dim3(1), dim3(256), 0, stream, bsum, bpre, offs);
    hipLaunchKernelGGL(k_scan3,    dim3(SCAN_NB), dim3(256), 0, stream, offs, bpre, curs, deg, dinv);
    hipLaunchKernelGGL(k_place,    dim3((NE + 255) / 256), dim3(256), 0, stream,
                       src, dst, dinv, curs, csrs, csrw);

    // layer 1: h = x @ W1 ; agg -> +b1, relu
    hipLaunchKernelGGL(k_gemm, dim3(2000), dim3(128), 0, stream, x, W1, hbuf);
    hipLaunchKernelGGL(k_agg,  dim3((NN * 64 + 255) / 256), dim3(256), 0, stream,
                       hbuf, dinv, offs, csrs, csrw, b1, abuf);
    // layer 2
    hipLaunchKernelGGL(k_gemm, dim3(2000), dim3(128), 0, stream, abuf, W2, hbuf);
    hipLaunchKernelGGL(k_agg,  dim3((NN * 64 + 255) / 256), dim3(256), 0, stream,
                       hbuf, dinv, offs, csrs, csrw, b2, out);
}